// Round 11
// baseline (3368.594 us; speedup 1.0000x reference)
//
#include <hip/hip_runtime.h>
#include <math.h>
#include <stdint.h>

#define BB 32
#define TT 1024
#define HH 128
#define G4 512   // 4*H
#define CH 16    // LSTM steps per LDS chunk
#define XPS 516  // xp row stride (floats): mult of 4 (b128 align)

typedef _Float16 half2_t __attribute__((ext_vector_type(2)));
typedef _Float16 half8_t __attribute__((ext_vector_type(8)));
typedef float f32x4 __attribute__((ext_vector_type(4)));

__device__ __forceinline__ float fdot2f(half2_t a, half2_t b, float c) {
    return __builtin_amdgcn_fdot2(a, b, c, false);
}
__device__ __forceinline__ float rcpf(float x) {
    return __builtin_amdgcn_rcpf(x);
}
// quad_perm DPP moves: VALU pipe, no LDS traffic
__device__ __forceinline__ float dpp_xor1(float x) {
    return __builtin_bit_cast(float, __builtin_amdgcn_update_dpp(
        0, __builtin_bit_cast(int, x), 0xB1, 0xF, 0xF, true));
}
__device__ __forceinline__ float dpp_xor2(float x) {
    return __builtin_bit_cast(float, __builtin_amdgcn_update_dpp(
        0, __builtin_bit_cast(int, x), 0x4E, 0xF, 0xF, true));
}
// barrier draining ONLY lgkmcnt — global loads (vmcnt) stay in flight
__device__ __forceinline__ void bar_lgkm() {
    asm volatile("s_waitcnt lgkmcnt(0)\n\ts_barrier" ::: "memory");
}
// full barrier (chunk handoff)
__device__ __forceinline__ void bar_full() {
    asm volatile("s_waitcnt vmcnt(0) lgkmcnt(0)\n\ts_barrier" ::: "memory");
}

// =============== one-shot: w_ih (NL x 2 x 512 x 256 fp32) -> f16 ===============
__global__ __launch_bounds__(256) void cvt_wih(
    const float* __restrict__ w, _Float16* __restrict__ o)
{
    const int i = (blockIdx.x * 256 + threadIdx.x) * 4;   // 512*256*4 = 524288 exact
    float4 f = *(const float4*)(w + i);
    half2_t t[2] = { half2_t{(_Float16)f.x, (_Float16)f.y},
                     half2_t{(_Float16)f.z, (_Float16)f.w} };
    *(float2*)(o + i) = *(float2*)t;
}

// =============== Fused LSTM layer: WAVE-SPECIALIZED producer/consumer ===============
// R10 post-mortem: 256-arch-VGPR ceiling makes a reg-resident W panel infeasible
// in the recurrence wave; 1 wave/SIMD exposes the serial chain. Conclusion after
// R4-R10: ANY projection work inside the recurrence wave's barrier window costs
// ~370cy/step. Fix (m114: separate waves overlap fully, time=max): 640-thread
// block. Waves 0-7 = R0-pure recurrence (zero filler instructions, 1490cy step).
// Waves 8-9 = producers: all 256 MFMA/chunk + W streamed from L2 on their own
// timeline (slot cost ~500cy << 1490cy -> always early at the barrier).
// Both paths execute IDENTICAL barrier sequences (16 bar_lgkm + 1 bar_full per
// chunk; wave-uniform branch) -> no divergent-barrier hazard.
__global__ __launch_bounds__(640) void lstm_fused(
    const float* __restrict__ x_in,       // B x T x 256 (layer input)
    const _Float16* __restrict__ wih16_l, // 2 x 512 x 256 (this layer, f16)
    const float* __restrict__ b_ih_l,     // 2 x 512
    const float* __restrict__ b_hh_l,     // 2 x 512
    const float* __restrict__ w_hh_l,     // 2 x 512 x 128
    float* __restrict__ out)              // B x T x 256  ([fwd|bwd] concat)
{
    const int b = blockIdx.x & 31;
    const int d = blockIdx.x >> 5;
    const int tid = threadIdx.x;          // 0..639
    const int wvid = tid >> 6;            // 0..9
    const int l = tid & 63;
    const bool isrec = wvid < 8;

    __shared__ __align__(16) _Float16 hs[HH];
    __shared__ __align__(16) float xp[2][CH * XPS];      // 66 KB gate-interleaved preacts
    __shared__ __align__(16) half2_t xr[2][CH * 128];    // 16 KB raw x in f16 (swizzled)
    __shared__ __align__(16) float obuf[CH * HH];        // 8 KB h output buffer

    const float* xbase = x_in + (size_t)b * TT * 256;

    // A-frag addressing (producers): byte = row*512 + kt*64 + (l>>4)*16, row=l&15
    const int a_noswz = (l & 15) * 512 + (l >> 4) * 16;
    const int a_swz   = (l & 7) << 4;
    // xr conversion-store swizzle (rec waves, 512 thr x 16B): row = tid>>5
    const int w_swz_byte = (tid * 16) ^ (((tid >> 5) & 7) << 4);

    // ---- prologue: rec waves stage raw chunks 0,1 -> xr (swizzled) ----
    if (isrec) {
#pragma unroll 1
        for (int p = 0; p < 2; ++p) {
            const int tlo = d ? (1008 - p * CH) : p * CH;
            const float* gs = xbase + (size_t)tlo * 256 + tid * 8;
            float4 f0 = *(const float4*)gs;
            float4 f1 = *(const float4*)(gs + 4);
            half2_t t4[4] = { half2_t{(_Float16)f0.x, (_Float16)f0.y},
                              half2_t{(_Float16)f0.z, (_Float16)f0.w},
                              half2_t{(_Float16)f1.x, (_Float16)f1.y},
                              half2_t{(_Float16)f1.z, (_Float16)f1.w} };
            *(float4*)((char*)xr[p] + w_swz_byte) = *(float4*)t4;
        }
        if (tid < 64) ((half2_t*)hs)[tid] = half2_t{(_Float16)0.f, (_Float16)0.f};
    }
    __syncthreads();   // BAR-A: xr[0], xr[1], hs staged

    if (isrec) {
        // ================= RECURRENCE PATH (waves 0-7): R0-pure =================
        const int s = l & 3;              // k-slice
        const int g = l >> 2;             // 0..15
        const int j = (wvid << 4) | g;    // 0..127

        // gate-rows 128G + j, k in [32s,32s+32), f16 (64 VGPRs)
        half2_t wv[4][16];
#pragma unroll
        for (int G = 0; G < 4; ++G) {
            const float* wr = w_hh_l + (size_t)(d * G4 + 128 * G + j) * HH + 32 * s;
#pragma unroll
            for (int q4 = 0; q4 < 8; ++q4) {
                float4 f = *(const float4*)(wr + 4 * q4);
                wv[G][2 * q4]     = half2_t{(_Float16)f.x, (_Float16)f.y};
                wv[G][2 * q4 + 1] = half2_t{(_Float16)f.z, (_Float16)f.w};
            }
        }
        float c = 0.f;
        float* ob = out + (size_t)b * TT * 256 + d * HH;

        __syncthreads();   // BAR-B: producers finished xp[0]

        float4 rg0 = {}, rg1 = {};
#pragma unroll 1
        for (int ck = 0; ck < 64; ++ck) {
            const int cur = ck & 1;
            if (ck + 2 < 64) {
                const int tlo2 = d ? (1008 - (ck + 2) * CH) : (ck + 2) * CH;
                const float* gs = xbase + (size_t)tlo2 * 256 + tid * 8;
                rg0 = *(const float4*)gs;
                rg1 = *(const float4*)(gs + 4);
            }
            const float* xb = xp[cur];

#pragma unroll 1
            for (int si = 0; si < CH; ++si) {
                const int lds_t = d ? (CH - 1 - si) : si;
                const float4 xg4 = *(const float4*)&xb[lds_t * XPS + (j << 2)];

                const float4* hp = (const float4*)(hs + 32 * s);
                float4 hA = hp[0], hB = hp[1], hC = hp[2], hD = hp[3];
                half2_t hh[16];
                hh[0]  = __builtin_bit_cast(half2_t, hA.x);
                hh[1]  = __builtin_bit_cast(half2_t, hA.y);
                hh[2]  = __builtin_bit_cast(half2_t, hA.z);
                hh[3]  = __builtin_bit_cast(half2_t, hA.w);
                hh[4]  = __builtin_bit_cast(half2_t, hB.x);
                hh[5]  = __builtin_bit_cast(half2_t, hB.y);
                hh[6]  = __builtin_bit_cast(half2_t, hB.z);
                hh[7]  = __builtin_bit_cast(half2_t, hB.w);
                hh[8]  = __builtin_bit_cast(half2_t, hC.x);
                hh[9]  = __builtin_bit_cast(half2_t, hC.y);
                hh[10] = __builtin_bit_cast(half2_t, hC.z);
                hh[11] = __builtin_bit_cast(half2_t, hC.w);
                hh[12] = __builtin_bit_cast(half2_t, hD.x);
                hh[13] = __builtin_bit_cast(half2_t, hD.y);
                hh[14] = __builtin_bit_cast(half2_t, hD.z);
                hh[15] = __builtin_bit_cast(half2_t, hD.w);

                float a0 = 0.f, a1 = 0.f, a2 = 0.f, a3 = 0.f;
                float e0 = 0.f, e1 = 0.f, e2 = 0.f, e3 = 0.f;
#pragma unroll
                for (int kk = 0; kk < 8; ++kk) {
                    a0 = fdot2f(wv[0][kk], hh[kk], a0);
                    a1 = fdot2f(wv[1][kk], hh[kk], a1);
                    a2 = fdot2f(wv[2][kk], hh[kk], a2);
                    a3 = fdot2f(wv[3][kk], hh[kk], a3);
                    e0 = fdot2f(wv[0][kk + 8], hh[kk + 8], e0);
                    e1 = fdot2f(wv[1][kk + 8], hh[kk + 8], e1);
                    e2 = fdot2f(wv[2][kk + 8], hh[kk + 8], e2);
                    e3 = fdot2f(wv[3][kk + 8], hh[kk + 8], e3);
                }
                a0 += e0; a1 += e1; a2 += e2; a3 += e3;

                a0 += dpp_xor1(a0); a0 += dpp_xor2(a0);
                a1 += dpp_xor1(a1); a1 += dpp_xor2(a1);
                a2 += dpp_xor1(a2); a2 += dpp_xor2(a2);
                a3 += dpp_xor1(a3); a3 += dpp_xor2(a3);

                const float gi = rcpf(1.f + __expf(-(a0 + xg4.x)));
                const float gf = rcpf(1.f + __expf(-(a1 + xg4.y)));
                const float gg = 1.f - 2.f * rcpf(1.f + __expf(2.f * (a2 + xg4.z)));
                const float go = rcpf(1.f + __expf(-(a3 + xg4.w)));
                c = gf * c + gi * gg;
                const float th = 1.f - 2.f * rcpf(1.f + __expf(2.f * c));
                const float h = go * th;
                if (s == 0) {
                    hs[j] = (_Float16)h;
                    obuf[si * HH + j] = h;
                }
                bar_lgkm();
            }

            // flush obuf (coalesced, 4 floats/thread over 512 threads)
            {
                const int idx = tid * 4;
                const int sf = idx >> 7, jf = idx & 127;
                const int sg = ck * CH + sf;
                const int t  = d ? (TT - 1 - sg) : sg;
                float4 o0 = *(const float4*)&obuf[idx];
                *(float4*)&ob[(size_t)t * 256 + jf] = o0;
            }
            // convert raw chunk ck+2 -> xr[cur] (swizzled)
            if (ck + 2 < 64) {
                half2_t t4[4] = { half2_t{(_Float16)rg0.x, (_Float16)rg0.y},
                                  half2_t{(_Float16)rg0.z, (_Float16)rg0.w},
                                  half2_t{(_Float16)rg1.x, (_Float16)rg1.y},
                                  half2_t{(_Float16)rg1.z, (_Float16)rg1.w} };
                *(float4*)((char*)xr[cur] + w_swz_byte) = *(float4*)t4;
            }
            bar_full();
        }
    } else {
        // ================= PRODUCER PATH (waves 8-9): projection =================
        const int pwave = wvid - 8;                 // 0,1
        const int pcol0 = pwave * 256 + (l & 15);   // base col of 16 n-tiles
        const _Float16* wn = wih16_l + ((size_t)d * G4 + pcol0) * 256 + (l >> 4) * 8;
        float bias[16];
        int cix[16];
#pragma unroll
        for (int nt = 0; nt < 16; ++nt) {
            const int n = pcol0 + 16 * nt;
            bias[nt] = b_ih_l[d * G4 + n] + b_hh_l[d * G4 + n];
            cix[nt] = ((n & 127) << 2) + (n >> 7);
        }
        const int rb = (l >> 4) * 4;

        f32x4 acc[16];
#pragma unroll
        for (int nt = 0; nt < 16; ++nt) acc[nt] = (f32x4){bias[nt], bias[nt], bias[nt], bias[nt]};

        // chunk-0 projection (straight-line, between BAR-A and BAR-B)
#pragma unroll
        for (int kt = 0; kt < 8; ++kt) {
            half8_t af = *(const half8_t*)((const char*)xr[0] + ((a_noswz + kt * 64) ^ a_swz));
#pragma unroll
            for (int nt = 0; nt < 16; ++nt)
                acc[nt] = __builtin_amdgcn_mfma_f32_16x16x32_f16(
                    af, *(const half8_t*)(wn + nt * 4096 + kt * 32), acc[nt], 0, 0, 0);
        }
#pragma unroll
        for (int nt = 0; nt < 16; ++nt) {
#pragma unroll
            for (int qq = 0; qq < 4; ++qq)
                xp[0][(rb + qq) * XPS + cix[nt]] = acc[nt][qq];
            acc[nt] = (f32x4){bias[nt], bias[nt], bias[nt], bias[nt]};
        }

        __syncthreads();   // BAR-B

#pragma unroll 1
        for (int ck = 0; ck < 64; ++ck) {
            const int cur = ck & 1;
            const bool doproj = (ck + 1 < 64);
            const char* xr_rd = (const char*)xr[cur ^ 1];   // raw x of chunk ck+1

            if (doproj) {
                half8_t afrag = {};
#pragma unroll
                for (int slot = 0; slot < CH; ++slot) {
                    const int kt = slot >> 1;
                    const int hbase = (slot & 1) * 8;
                    if (!(slot & 1))
                        afrag = *(const half8_t*)(xr_rd + ((a_noswz + kt * 64) ^ a_swz));
                    half8_t bf[8];
#pragma unroll
                    for (int i = 0; i < 8; ++i)
                        bf[i] = *(const half8_t*)(wn + (hbase + i) * 4096 + kt * 32);
#pragma unroll
                    for (int i = 0; i < 8; ++i)
                        acc[hbase + i] = __builtin_amdgcn_mfma_f32_16x16x32_f16(
                            afrag, bf[i], acc[hbase + i], 0, 0, 0);
                    bar_lgkm();
                }
                // C-flush for chunk ck+1; reinit
                float* xpn = xp[cur ^ 1];
#pragma unroll
                for (int nt = 0; nt < 16; ++nt) {
#pragma unroll
                    for (int qq = 0; qq < 4; ++qq)
                        xpn[(rb + qq) * XPS + cix[nt]] = acc[nt][qq];
                    acc[nt] = (f32x4){bias[nt], bias[nt], bias[nt], bias[nt]};
                }
            } else {
#pragma unroll
                for (int slot = 0; slot < CH; ++slot) bar_lgkm();
            }
            bar_full();
        }
    }
}

// =============== Attention (last-row only) + FC — 1024 threads ===============
__global__ __launch_bounds__(1024) void attn_kernel(
    const float* __restrict__ out1,  // B x T x 256
    const float* __restrict__ wq, const float* __restrict__ bq,
    const float* __restrict__ wk,
    const float* __restrict__ wv, const float* __restrict__ bv,
    const float* __restrict__ wfc, const float* __restrict__ bfc,
    float* __restrict__ outp)        // B x 4
{
    const int b = blockIdx.x;
    const int tid = threadIdx.x;
    const int n = tid & 255, qq = tid >> 8;   // col, quarter

    __shared__ float xl[256], q[256], u[256], cx[256];
    __shared__ __align__(16) float r[256];
    __shared__ float sc[TT];
    __shared__ float red[1024];
    __shared__ float part[4][256];

    const float* ob = out1 + (size_t)b * TT * 256;

    if (tid < 256) xl[tid] = ob[(size_t)(TT - 1) * 256 + tid];
    __syncthreads();

    // q[n] = bq[n] + xl . wq[n,:]
    {
        float a = 0.f;
        const float* wr = wq + (size_t)n * 256 + qq * 64;
        const float* xq = xl + qq * 64;
#pragma unroll 8
        for (int k = 0; k < 64; ++k) a += xq[k] * wr[k];
        part[qq][n] = a;
    }
    __syncthreads();
    if (tid < 256) q[tid] = bq[tid] + part[0][tid] + part[1][tid] + part[2][tid] + part[3][tid];
    __syncthreads();

    // r[n] = sum_d q[d] * wk[d,n]
    {
        float a = 0.f;
        const float* wkp = wk + (size_t)(qq * 64) * 256 + n;
#pragma unroll 8
        for (int dd = 0; dd < 64; ++dd) a += q[qq * 64 + dd] * wkp[(size_t)dd * 256];
        part[qq][n] = a;
    }
    __syncthreads();
    if (tid < 256) r[tid] = part[0][tid] + part[1][tid] + part[2][tid] + part[3][tid];
    __syncthreads();

    // scores: sc[t] = (r . out1[b,t,:]) / 16
    {
        const int wave = tid >> 6, lane = tid & 63;
        float4 r4 = *(const float4*)&r[lane * 4];
        for (int t = wave; t < TT; t += 16) {
            float4 o4 = *(const float4*)(ob + (size_t)t * 256 + lane * 4);
            float p = r4.x * o4.x + r4.y * o4.y + r4.z * o4.z + r4.w * o4.w;
#pragma unroll
            for (int off = 32; off > 0; off >>= 1) p += __shfl_down(p, off, 64);
            if (lane == 0) sc[t] = p * 0.0625f;
        }
    }
    __syncthreads();

    // softmax over sc[0..1023] — one element per thread
    float v = sc[tid];
    red[tid] = v; __syncthreads();
    for (int st = 512; st > 0; st >>= 1) {
        if (tid < st) red[tid] = fmaxf(red[tid], red[tid + st]);
        __syncthreads();
    }
    const float mx = red[0]; __syncthreads();
    const float e = expf(v - mx);
    sc[tid] = e;
    red[tid] = e; __syncthreads();
    for (int st = 512; st > 0; st >>= 1) {
        if (tid < st) red[tid] += red[tid + st];
        __syncthreads();
    }
    const float inv = 1.f / red[0];
    __syncthreads();

    // ctx: u[n] = inv * sum_t sc[t] * out1[b,t,n]
    {
        float a = 0.f;
        const float* op = ob + (size_t)(qq * 256) * 256 + n;
        const float* sp = sc + qq * 256;
#pragma unroll 4
        for (int t = 0; t < 256; ++t) a += sp[t] * op[(size_t)t * 256];
        part[qq][n] = a;
    }
    __syncthreads();
    if (tid < 256) u[tid] = (part[0][tid] + part[1][tid] + part[2][tid] + part[3][tid]) * inv;
    __syncthreads();

    // cx[n] = bv[n] + u . wv[n,:]
    {
        float a = 0.f;
        const float* wr = wv + (size_t)n * 256 + qq * 64;
#pragma unroll 8
        for (int k = 0; k < 64; ++k) a += u[qq * 64 + k] * wr[k];
        part[qq][n] = a;
    }
    __syncthreads();
    if (tid < 256) cx[tid] = bv[tid] + part[0][tid] + part[1][tid] + part[2][tid] + part[3][tid];
    __syncthreads();

    if (tid < 4) {
        float o = bfc[tid];
        for (int k = 0; k < 256; ++k) o += cx[k] * wfc[tid * 256 + k];
        outp[b * 4 + tid] = o;
    }
}

extern "C" void kernel_launch(void* const* d_in, const int* in_sizes, int n_in,
                              void* d_out, int out_size, void* d_ws, size_t ws_size,
                              hipStream_t stream)
{
    const float* x    = (const float*)d_in[0];
    const float* w_ih = (const float*)d_in[1];
    const float* w_hh = (const float*)d_in[2];
    const float* b_ih = (const float*)d_in[3];
    const float* b_hh = (const float*)d_in[4];
    const float* wq   = (const float*)d_in[5];
    const float* wk   = (const float*)d_in[6];
    const float* wv   = (const float*)d_in[7];
    const float* bq   = (const float*)d_in[8];
    const float* bv   = (const float*)d_in[10];
    const float* wfc  = (const float*)d_in[11];
    const float* bfcv = (const float*)d_in[12];
    float* outp = (float*)d_out;

    float* ws = (float*)d_ws;
    _Float16* wih16 = (_Float16*)ws;          // 2*2*512*256 f16 = 1 MB (262144 floats)
    float* out0 = ws + 262144;                // 8,388,608 floats (32 MB)
    float* out1 = out0 + 8388608;             // 8,388,608 floats (32 MB)

    // one-shot weight conversion: 2*2*512*256 = 524288 = 512*256*4
    cvt_wih<<<512, 256, 0, stream>>>(w_ih, wih16);

    lstm_fused<<<64, 640, 0, stream>>>(x, wih16, b_ih, b_hh, w_hh, out0);
    lstm_fused<<<64, 640, 0, stream>>>(out0, wih16 + 262144, b_ih + 1024, b_hh + 1024,
                                       w_hh + 2 * 512 * 128, out1);
    attn_kernel<<<32, 1024, 0, stream>>>(out1, wq, bq, wk, wv, bv, wfc, bfcv, outp);
}

// Round 12
// 1679.240 us; speedup vs baseline: 2.0060x; 2.0060x over previous
//
#include <hip/hip_runtime.h>
#include <math.h>
#include <stdint.h>

#define BB 32
#define TT 1024
#define HH 128
#define G4 512   // 4*H
#define CH 16    // LSTM steps per LDS chunk
#define XPS 516  // xp row stride (floats): mult of 4 (b128 align)

typedef _Float16 half2_t __attribute__((ext_vector_type(2)));
typedef _Float16 half8_t __attribute__((ext_vector_type(8)));
typedef float f32x4 __attribute__((ext_vector_type(4)));

__device__ __forceinline__ float fdot2f(half2_t a, half2_t b, float c) {
    return __builtin_amdgcn_fdot2(a, b, c, false);
}
__device__ __forceinline__ float rcpf(float x) {
    return __builtin_amdgcn_rcpf(x);
}
// quad_perm DPP moves: VALU pipe, no LDS traffic
__device__ __forceinline__ float dpp_xor1(float x) {
    return __builtin_bit_cast(float, __builtin_amdgcn_update_dpp(
        0, __builtin_bit_cast(int, x), 0xB1, 0xF, 0xF, true));
}
__device__ __forceinline__ float dpp_xor2(float x) {
    return __builtin_bit_cast(float, __builtin_amdgcn_update_dpp(
        0, __builtin_bit_cast(int, x), 0x4E, 0xF, 0xF, true));
}
// workgroup barrier draining ONLY lgkmcnt — global loads (vmcnt) stay in flight
__device__ __forceinline__ void bar_lgkm() {
    asm volatile("s_waitcnt lgkmcnt(0)\n\ts_barrier" ::: "memory");
}

// =============== one-shot: w_ih (NL x 2 x 512 x 256 fp32) -> f16 ===============
__global__ __launch_bounds__(256) void cvt_wih(
    const float* __restrict__ w, _Float16* __restrict__ o)
{
    const int i = (blockIdx.x * 256 + threadIdx.x) * 4;   // 512*256*4 = 524288 exact
    float4 f = *(const float4*)(w + i);
    half2_t t[2] = { half2_t{(_Float16)f.x, (_Float16)f.y},
                     half2_t{(_Float16)f.z, (_Float16)f.w} };
    *(float2*)(o + i) = *(float2*)t;
}

// =============== Fused LSTM layer: R7 (best verified: 793us, VGPR 112) ===============
// Even/odd register sets with 2-step unroll: each global B-frag pair is WRITTEN
// in one step parity and READ in the other (no copies), so issue->use >= one
// full recurrence body. A-frag same-step (LDS, covered by recurrence VALU).
// R8-R11 post-mortems: reg-resident W panel infeasible (256 arch-VGPR ceiling,
// allocator spills at every block size); wave specialization infeasible (flat
// per-kernel allocation starves the producer path). This is the plateau of the
// fused design at HIP source level.
__global__ __launch_bounds__(512, 1) void lstm_fused(
    const float* __restrict__ x_in,       // B x T x 256 (layer input)
    const _Float16* __restrict__ wih16_l, // 2 x 512 x 256 (this layer, f16)
    const float* __restrict__ b_ih_l,     // 2 x 512
    const float* __restrict__ b_hh_l,     // 2 x 512
    const float* __restrict__ w_hh_l,     // 2 x 512 x 128
    float* __restrict__ out)              // B x T x 256  ([fwd|bwd] concat)
{
    const int b = blockIdx.x & 31;
    const int d = blockIdx.x >> 5;
    const int tid = threadIdx.x;
    const int wvid = tid >> 6;
    const int l = tid & 63;
    const int s = l & 3;              // k-slice
    const int g = l >> 2;             // 0..15
    const int j = (wvid << 4) | g;    // 0..127 : h element owned by this quad

    __shared__ __align__(16) _Float16 hs[HH];
    __shared__ __align__(16) float xp[2][CH * XPS];      // 66 KB gate-interleaved preacts
    __shared__ __align__(16) half2_t xr[2][CH * 128];    // 16 KB raw x in f16 (swizzled)
    __shared__ __align__(16) float obuf[CH * HH];        // 8 KB h output buffer

    // ---- recurrence weights: gate-rows 128G + j, k in [32s, 32s+32), as f16 ----
    half2_t wv[4][16];
#pragma unroll
    for (int G = 0; G < 4; ++G) {
        const float* wr = w_hh_l + (size_t)(d * G4 + 128 * G + j) * HH + 32 * s;
#pragma unroll
        for (int q4 = 0; q4 < 8; ++q4) {
            float4 f = *(const float4*)(wr + 4 * q4);
            wv[G][2 * q4]     = half2_t{(_Float16)f.x, (_Float16)f.y};
            wv[G][2 * q4 + 1] = half2_t{(_Float16)f.z, (_Float16)f.w};
        }
    }

    // ---- MFMA projection setup: wave owns cols [wvid*64, +64) ----
    const int acol0 = wvid * 64 + (l & 15);
    const _Float16* wn = wih16_l + ((size_t)d * G4 + acol0) * 256 + (l >> 4) * 8;
    const float bias0 = b_ih_l[d * G4 + acol0]      + b_hh_l[d * G4 + acol0];
    const float bias1 = b_ih_l[d * G4 + acol0 + 16] + b_hh_l[d * G4 + acol0 + 16];
    const float bias2 = b_ih_l[d * G4 + acol0 + 32] + b_hh_l[d * G4 + acol0 + 32];
    const float bias3 = b_ih_l[d * G4 + acol0 + 48] + b_hh_l[d * G4 + acol0 + 48];

    // gate-interleaved store index: n -> row*XPS + (n&127)*4 + (n>>7)
    const int cbase = ((acol0 & 127) << 2) + (acol0 >> 7);

    const float* xbase = x_in + (size_t)b * TT * 256;

    // A-frag addressing: logical byte = row*512 + kt*64 + (l>>4)*16, row = l&15
    const int a_noswz = (l & 15) * 512 + (l >> 4) * 16;
    const int a_swz   = (l & 7) << 4;
    // xr writer: thread writes t = tid>>5, 16B at tid*16; swizzle by row&7
    const int w_swz_byte = (tid * 16) ^ (((tid >> 5) & 7) << 4);

    // ---- prologue: stage raw chunks 0,1 -> xr (swizzled) ----
#pragma unroll 1
    for (int p = 0; p < 2; ++p) {
        const int tlo = d ? (1008 - p * CH) : p * CH;
        const float* gs = xbase + (size_t)tlo * 256 + tid * 8;
        float4 f0 = *(const float4*)gs;
        float4 f1 = *(const float4*)(gs + 4);
        half2_t t4[4] = { half2_t{(_Float16)f0.x, (_Float16)f0.y},
                          half2_t{(_Float16)f0.z, (_Float16)f0.w},
                          half2_t{(_Float16)f1.x, (_Float16)f1.y},
                          half2_t{(_Float16)f1.z, (_Float16)f1.w} };
        *(float4*)((char*)xr[p] + w_swz_byte) = *(float4*)t4;
    }
    __syncthreads();

    f32x4 acc0 = {bias0, bias0, bias0, bias0};
    f32x4 acc1 = {bias1, bias1, bias1, bias1};
    f32x4 acc2 = {bias2, bias2, bias2, bias2};
    f32x4 acc3 = {bias3, bias3, bias3, bias3};

    // ---- chunk-0 projection: straight-line 8 ktiles x 4 ntiles ----
#pragma unroll
    for (int kt = 0; kt < 8; ++kt) {
        half8_t af = *(const half8_t*)((const char*)xr[0] + ((a_noswz + kt * 64) ^ a_swz));
        acc0 = __builtin_amdgcn_mfma_f32_16x16x32_f16(af, *(const half8_t*)(wn +         kt * 32), acc0, 0, 0, 0);
        acc1 = __builtin_amdgcn_mfma_f32_16x16x32_f16(af, *(const half8_t*)(wn +  4096 + kt * 32), acc1, 0, 0, 0);
        acc2 = __builtin_amdgcn_mfma_f32_16x16x32_f16(af, *(const half8_t*)(wn +  8192 + kt * 32), acc2, 0, 0, 0);
        acc3 = __builtin_amdgcn_mfma_f32_16x16x32_f16(af, *(const half8_t*)(wn + 12288 + kt * 32), acc3, 0, 0, 0);
    }
    {
        const int rb = (l >> 4) * 4;
#pragma unroll
        for (int q = 0; q < 4; ++q) {
            const int ix = (rb + q) * XPS + cbase;
            xp[0][ix]       = acc0[q];
            xp[0][ix + 64]  = acc1[q];
            xp[0][ix + 128] = acc2[q];
            xp[0][ix + 192] = acc3[q];
        }
    }
    acc0 = (f32x4){bias0, bias0, bias0, bias0};
    acc1 = (f32x4){bias1, bias1, bias1, bias1};
    acc2 = (f32x4){bias2, bias2, bias2, bias2};
    acc3 = (f32x4){bias3, bias3, bias3, bias3};

    if (tid < 64) ((half2_t*)hs)[tid] = half2_t{(_Float16)0.f, (_Float16)0.f};
    float c = 0.f;   // replicated across the quad
    float* ob = out + (size_t)b * TT * 256 + d * HH;
    __syncthreads();   // xp[0], hs visible

    float4 rg0 = {}, rg1 = {};
    for (int ck = 0; ck < 64; ++ck) {
        const int cur = ck & 1;
        const bool doproj = (ck + 1 < 64);
        // issue raw-x loads for chunk ck+2 (vmcnt survives per-step lgkm barriers)
        if (ck + 2 < 64) {
            const int tlo2 = d ? (1008 - (ck + 2) * CH) : (ck + 2) * CH;
            const float* gs = xbase + (size_t)tlo2 * 256 + tid * 8;
            rg0 = *(const float4*)gs;
            rg1 = *(const float4*)(gs + 4);
        }
        const float* xb = xp[cur];
        const char* xr_rd = (const char*)xr[cur ^ 1];   // raw x of chunk ck+1

        // one full recurrence step (si): reads xb/hs, updates c, writes hs/obuf
        auto rec_step = [&](int si) {
            const int lds_t = d ? (CH - 1 - si) : si;
            const float4 xg4 = *(const float4*)&xb[lds_t * XPS + (j << 2)];

            const float4* hp = (const float4*)(hs + 32 * s);
            float4 hA = hp[0], hB = hp[1], hC = hp[2], hD = hp[3];
            half2_t hh[16];
            hh[0]  = __builtin_bit_cast(half2_t, hA.x);
            hh[1]  = __builtin_bit_cast(half2_t, hA.y);
            hh[2]  = __builtin_bit_cast(half2_t, hA.z);
            hh[3]  = __builtin_bit_cast(half2_t, hA.w);
            hh[4]  = __builtin_bit_cast(half2_t, hB.x);
            hh[5]  = __builtin_bit_cast(half2_t, hB.y);
            hh[6]  = __builtin_bit_cast(half2_t, hB.z);
            hh[7]  = __builtin_bit_cast(half2_t, hB.w);
            hh[8]  = __builtin_bit_cast(half2_t, hC.x);
            hh[9]  = __builtin_bit_cast(half2_t, hC.y);
            hh[10] = __builtin_bit_cast(half2_t, hC.z);
            hh[11] = __builtin_bit_cast(half2_t, hC.w);
            hh[12] = __builtin_bit_cast(half2_t, hD.x);
            hh[13] = __builtin_bit_cast(half2_t, hD.y);
            hh[14] = __builtin_bit_cast(half2_t, hD.z);
            hh[15] = __builtin_bit_cast(half2_t, hD.w);

            float a0 = 0.f, a1 = 0.f, a2 = 0.f, a3 = 0.f;
            float e0 = 0.f, e1 = 0.f, e2 = 0.f, e3 = 0.f;
#pragma unroll
            for (int kk = 0; kk < 8; ++kk) {
                a0 = fdot2f(wv[0][kk], hh[kk], a0);
                a1 = fdot2f(wv[1][kk], hh[kk], a1);
                a2 = fdot2f(wv[2][kk], hh[kk], a2);
                a3 = fdot2f(wv[3][kk], hh[kk], a3);
                e0 = fdot2f(wv[0][kk + 8], hh[kk + 8], e0);
                e1 = fdot2f(wv[1][kk + 8], hh[kk + 8], e1);
                e2 = fdot2f(wv[2][kk + 8], hh[kk + 8], e2);
                e3 = fdot2f(wv[3][kk + 8], hh[kk + 8], e3);
            }
            a0 += e0; a1 += e1; a2 += e2; a3 += e3;

            a0 += dpp_xor1(a0); a0 += dpp_xor2(a0);
            a1 += dpp_xor1(a1); a1 += dpp_xor2(a1);
            a2 += dpp_xor1(a2); a2 += dpp_xor2(a2);
            a3 += dpp_xor1(a3); a3 += dpp_xor2(a3);

            const float gi = rcpf(1.f + __expf(-(a0 + xg4.x)));
            const float gf = rcpf(1.f + __expf(-(a1 + xg4.y)));
            const float gg = 1.f - 2.f * rcpf(1.f + __expf(2.f * (a2 + xg4.z)));
            const float go = rcpf(1.f + __expf(-(a3 + xg4.w)));
            c = gf * c + gi * gg;
            const float th = 1.f - 2.f * rcpf(1.f + __expf(2.f * c));
            const float h = go * th;
            if (s == 0) {
                hs[j] = (_Float16)h;
                obuf[si * HH + j] = h;
            }
        };

        // ---- even/odd pipelined operand sets (no copies): E-set consumed in
        //      even steps / written in odd; O-set the reverse ----
        half8_t gbEA = {}, gbEB = {}, gbOA = {}, gbOB = {};
        if (doproj) {
            gbEA = *(const half8_t*)(wn);          // step 0 operands
            gbEB = *(const half8_t*)(wn + 4096);
        }

#pragma unroll 1
        for (int sp = 0; sp < CH / 2; ++sp) {
            const int kt = sp;
            half8_t afrag = {};
            // ======== EVEN step si = 2*sp ========
            if (doproj) {
                afrag = *(const half8_t*)(xr_rd + ((a_noswz + kt * 64) ^ a_swz));
                gbOA = *(const half8_t*)(wn +  8192 + kt * 32);   // for odd step
                gbOB = *(const half8_t*)(wn + 12288 + kt * 32);
            }
            rec_step(2 * sp);
            if (doproj) {
                acc0 = __builtin_amdgcn_mfma_f32_16x16x32_f16(afrag, gbEA, acc0, 0, 0, 0);
                acc1 = __builtin_amdgcn_mfma_f32_16x16x32_f16(afrag, gbEB, acc1, 0, 0, 0);
            }
            bar_lgkm();
            // ======== ODD step si = 2*sp+1 ========
            if (doproj) {
                const int ktn = (kt + 1) & 7;                     // for next even step
                gbEA = *(const half8_t*)(wn +        ktn * 32);
                gbEB = *(const half8_t*)(wn + 4096 + ktn * 32);
            }
            rec_step(2 * sp + 1);
            if (doproj) {
                acc2 = __builtin_amdgcn_mfma_f32_16x16x32_f16(afrag, gbOA, acc2, 0, 0, 0);
                acc3 = __builtin_amdgcn_mfma_f32_16x16x32_f16(afrag, gbOB, acc3, 0, 0, 0);
            }
            bar_lgkm();
        }

        // flush obuf for chunk ck (coalesced, 4 floats/thread)
        {
            const int idx = tid * 4;
            const int sf = idx >> 7, jf = idx & 127;
            const int sg = ck * CH + sf;
            const int t  = d ? (TT - 1 - sg) : sg;
            float4 o0 = *(const float4*)&obuf[idx];
            *(float4*)&ob[(size_t)t * 256 + jf] = o0;
        }
        // flush projected preacts (C frags, gate-interleaved) for chunk ck+1
        if (doproj) {
            float* xpn = xp[cur ^ 1];
            const int rb = (l >> 4) * 4;
#pragma unroll
            for (int q = 0; q < 4; ++q) {
                const int ix = (rb + q) * XPS + cbase;
                xpn[ix]       = acc0[q];
                xpn[ix + 64]  = acc1[q];
                xpn[ix + 128] = acc2[q];
                xpn[ix + 192] = acc3[q];
            }
            acc0 = (f32x4){bias0, bias0, bias0, bias0};
            acc1 = (f32x4){bias1, bias1, bias1, bias1};
            acc2 = (f32x4){bias2, bias2, bias2, bias2};
            acc3 = (f32x4){bias3, bias3, bias3, bias3};
        }
        // convert raw chunk ck+2 -> xr[cur] (swizzled; consumed during ck+1)
        if (ck + 2 < 64) {
            half2_t t4[4] = { half2_t{(_Float16)rg0.x, (_Float16)rg0.y},
                              half2_t{(_Float16)rg0.z, (_Float16)rg0.w},
                              half2_t{(_Float16)rg1.x, (_Float16)rg1.y},
                              half2_t{(_Float16)rg1.z, (_Float16)rg1.w} };
            *(float4*)((char*)xr[cur] + w_swz_byte) = *(float4*)t4;
        }
        __syncthreads();   // full drain: xp/xr/obuf handoff
    }
}

// =============== Attention, 3-kernel split ===============
// R11 decision: attn was one 32-block phase-serial kernel (~90us). Split so the
// heavy score/ctx phases run on 256 blocks. Softmax uses NO max subtraction
// (scores ~0.06 magnitude: r ~ 0.2, out ~ 0.3, /16 folded into r) -> single
// pass with atomic partial denominator/numerator reduction across t-blocks.

// K1: q = xl@wq^T + bq ; r = (q^T wk) / 16 -> ws. Also zeros ctx accumulators.
__global__ __launch_bounds__(256) void attn_qr(
    const float* __restrict__ out1, const float* __restrict__ wq,
    const float* __restrict__ bq,   const float* __restrict__ wk,
    float* __restrict__ r_ws, float* __restrict__ ctxw, float* __restrict__ den)
{
    const int b = blockIdx.x;
    const int tid = threadIdx.x;
    __shared__ float xl[256], q[256];
    const float* ob = out1 + (size_t)b * TT * 256;

    xl[tid] = ob[(size_t)(TT - 1) * 256 + tid];
    ctxw[b * 256 + tid] = 0.f;
    if (tid == 0) den[b] = 0.f;
    __syncthreads();

    float acc = bq[tid];
    const float* wqr = wq + (size_t)tid * 256;
#pragma unroll 4
    for (int k = 0; k < 256; ++k) acc += xl[k] * wqr[k];
    q[tid] = acc;
    __syncthreads();

    acc = 0.f;
#pragma unroll 4
    for (int dd = 0; dd < 256; ++dd) acc += q[dd] * wk[(size_t)dd * 256 + tid];
    r_ws[b * 256 + tid] = acc * 0.0625f;   // fold the 1/sqrt(256)
}

// K2: 256 blocks = (b, s8): scores for 128 t, exp (no max), partial den + ctx.
__global__ __launch_bounds__(256) void attn_sc(
    const float* __restrict__ out1, const float* __restrict__ r_ws,
    float* __restrict__ ctxw, float* __restrict__ den)
{
    const int b  = blockIdx.x >> 3;
    const int s8 = blockIdx.x & 7;
    const int tid = threadIdx.x;
    __shared__ __align__(16) float r[256];
    __shared__ float ev[128];
    __shared__ float red[256];

    const float* ob = out1 + (size_t)b * TT * 256 + (size_t)s8 * 128 * 256;
    r[tid] = r_ws[b * 256 + tid];
    __syncthreads();

    const int wave = tid >> 6, lane = tid & 63;
    float4 r4 = *(const float4*)&r[lane * 4];
    for (int t = wave; t < 128; t += 4) {
        float4 o4 = *(const float4*)(ob + (size_t)t * 256 + lane * 4);
        float p = r4.x * o4.x + r4.y * o4.y + r4.z * o4.z + r4.w * o4.w;
#pragma unroll
        for (int off = 32; off > 0; off >>= 1) p += __shfl_down(p, off, 64);
        if (lane == 0) ev[t] = expf(p);
    }
    __syncthreads();

    // partial denominator
    red[tid] = (tid < 128) ? ev[tid] : 0.f;
    __syncthreads();
    for (int st = 128; st > 0; st >>= 1) {
        if (tid < st) red[tid] += red[tid + st];
        __syncthreads();
    }
    if (tid == 0) atomicAdd(&den[b], red[0]);

    // partial ctx numerator (coalesced over n = tid)
    float a = 0.f;
#pragma unroll 4
    for (int t = 0; t < 128; ++t) a += ev[t] * ob[(size_t)t * 256 + tid];
    atomicAdd(&ctxw[b * 256 + tid], a);
}

// K3: u = ctx/den ; cx = u@wv^T + bv ; out = cx@wfc^T + bfc.
__global__ __launch_bounds__(256) void attn_fc(
    const float* __restrict__ ctxw, const float* __restrict__ den,
    const float* __restrict__ wv,   const float* __restrict__ bv,
    const float* __restrict__ wfc,  const float* __restrict__ bfc,
    float* __restrict__ outp)
{
    const int b = blockIdx.x;
    const int tid = threadIdx.x;
    __shared__ float u[256], cx[256];

    u[tid] = ctxw[b * 256 + tid] / den[b];
    __syncthreads();

    float acc = bv[tid];
    const float* wr = wv + (size_t)tid * 256;
#pragma unroll 4
    for (int k = 0; k < 256; ++k) acc += u[k] * wr[k];
    cx[tid] = acc;
    __syncthreads();

    if (tid < 4) {
        float o = bfc[tid];
        for (int k = 0; k < 256; ++k) o += cx[k] * wfc[tid * 256 + k];
        outp[b * 4 + tid] = o;
    }
}

extern "C" void kernel_launch(void* const* d_in, const int* in_sizes, int n_in,
                              void* d_out, int out_size, void* d_ws, size_t ws_size,
                              hipStream_t stream)
{
    const float* x    = (const float*)d_in[0];
    const float* w_ih = (const float*)d_in[1];
    const float* w_hh = (const float*)d_in[2];
    const float* b_ih = (const float*)d_in[3];
    const float* b_hh = (const float*)d_in[4];
    const float* wq   = (const float*)d_in[5];
    const float* wk   = (const float*)d_in[6];
    const float* wv   = (const float*)d_in[7];
    const float* bq   = (const float*)d_in[8];
    const float* bv   = (const float*)d_in[10];
    const float* wfc  = (const float*)d_in[11];
    const float* bfcv = (const float*)d_in[12];
    float* outp = (float*)d_out;

    float* ws = (float*)d_ws;
    _Float16* wih16 = (_Float16*)ws;          // 2*2*512*256 f16 = 1 MB (262144 floats)
    float* out0 = ws + 262144;                // 8,388,608 floats (32 MB)
    float* out1 = out0 + 8388608;             // 8,388,608 floats (32 MB)
    float* r_ws = out1 + 8388608;             // 32*256 floats
    float* ctxw = r_ws + 8192;                // 32*256 floats
    float* den  = ctxw + 8192;                // 32 floats

    // one-shot weight conversion: 2*2*512*256 = 524288 = 512*256*4
    cvt_wih<<<512, 256, 0, stream>>>(w_ih, wih16);

    lstm_fused<<<64, 512, 0, stream>>>(x, wih16, b_ih, b_hh, w_hh, out0);
    lstm_fused<<<64, 512, 0, stream>>>(out0, wih16 + 262144, b_ih + 1024, b_hh + 1024,
                                       w_hh + 2 * 512 * 128, out1);

    attn_qr<<<32, 256, 0, stream>>>(out1, wq, bq, wk, r_ws, ctxw, den);
    attn_sc<<<256, 256, 0, stream>>>(out1, r_ws, ctxw, den);
    attn_fc<<<32, 256, 0, stream>>>(ctxw, den, wv, bv, wfc, bfcv, outp);
}